// Round 11
// baseline (180.867 us; speedup 1.0000x reference)
//
#include <hip/hip_runtime.h>
#include <hip/hip_bf16.h>

typedef __attribute__((ext_vector_type(8))) short short8;
typedef __attribute__((ext_vector_type(4))) float f32x4;
typedef __attribute__((ext_vector_type(16))) float f32x16;

#define NEG_SLOPE 0.02f

static __device__ __forceinline__ unsigned short f2bf(float f) {
    unsigned int u = __float_as_uint(f);
    u += 0x7fffu + ((u >> 16) & 1u);
    return (unsigned short)(u >> 16);
}

// pack two f32 -> one dword of 2 bf16 (lo, hi) via v_cvt_pk_bf16_f32
static __device__ __forceinline__ unsigned int pk2bf(float lo, float hi) {
    __hip_bfloat162 t = __float22bfloat162_rn(float2{lo, hi});
    unsigned int u;
    __builtin_memcpy(&u, &t, 4);
    return u;
}

#define WROW 300         // elems per co row: 288 used + 12 pad; 150 dw stride == 22 mod 32
#define ROW_BYTES 8320   // 65 pairs * 128

// ---------------- prep: weight transforms ----------------
// wb: [cc][co][WROW]  bf16, wb[cc][co][tap*32+ci5] = conv_w[co][cc*32+ci5][tap], pad=0
// pwb[o][k] = bf16(pred_w[o][k]) for o<24, 0 pad to 32 rows  (32*768 bf16)
__global__ __launch_bounds__(256) void prep_kernel(const float* __restrict__ conv_w,
                                                   const float* __restrict__ pred_w,
                                                   unsigned short* __restrict__ wb,
                                                   unsigned short* __restrict__ pwb) {
    int i = blockIdx.x * 256 + threadIdx.x;
    if (i < 2 * 64 * WROW) {
        int cc = i / (64 * WROW);
        int rem = i - cc * (64 * WROW);
        int co = rem / WROW, e = rem - co * WROW;
        float v = 0.0f;
        if (e < 288) {
            int tap = e >> 5, ci5 = e & 31;
            v = conv_w[(co * 64 + cc * 32 + ci5) * 9 + tap];
        }
        wb[i] = f2bf(v);
    }
    if (i < 24576) {
        int o = i / 768, k = i - o * 768;
        pwb[i] = f2bf(o < 24 ? pred_w[o * 768 + k] : 0.0f);
    }
}

// ---------------- fused conv 3x3 + bias + leaky relu (NCHW f32 in, NHWC bf16 out) ----------------
// block: 512 thr = 8 waves; 2 output rows x 128 px x 64 co. wave = 32 px x 64 co via
// mfma_f32_32x32x16_bf16: 1 m-tile(32 px) x 2 n-tiles(32 co), acc = 2 x f32x16 = 32 regs.
// LDS: weights [64co][WROW] 38,400 B + input 4 rows x 65 pairs x 128 B = 33,280 B
//      = 71,680 B -> 2 blocks/CU, 4 waves/SIMD.
// Staging: thread = 2 adjacent px x 8 ci -> 8 float2 loads (wave = one full 512B x-row
// per instr) -> 8 cvt_pk -> 2 ds_write_b128 (conflict-free per bank ledger).
// in_sm slot map (proven): pair stride 128 B, slot = ((xx&1)<<2 | ci_oct) ^ ((xx>>1)&7).
__global__ __launch_bounds__(512, 4) void conv_mfma(const float* __restrict__ x,
                                                    const unsigned short* __restrict__ wb,
                                                    const float* __restrict__ cb,
                                                    unsigned short* __restrict__ h) {
    __shared__ unsigned short w_sm[64 * WROW];       // 38,400 B
    __shared__ unsigned char in_sm[4 * ROW_BYTES];   // 33,280 B

    // XCD-chunked swizzle: each XCD owns 16 contiguous y rows (8 y-pairs) x all b
    const int id = blockIdx.x;                       // 2048 blocks
    const int xcd = id & 7, local = id >> 3;
    const int b = local & 31;
    const int y0 = ((xcd << 3) + (local >> 5)) * 2;

    const int tid = threadIdx.x;
    const int wave = tid >> 6, lane = tid & 63;
    const int l31 = lane & 31, hi = lane >> 5;
    const int ro = wave >> 2;                        // output row within block (0/1)
    const int px0 = (wave & 3) * 32;                 // px quarter
    const int y = y0 + ro;

    f32x16 acc[2];
#pragma unroll
    for (int n = 0; n < 2; ++n)
#pragma unroll
        for (int e = 0; e < 16; ++e) acc[n][e] = 0.0f;

    // A-frag pointers [dx][kstep]: xx = px0 + (lane&31) + dx, ci oct = ks*2 + hi
    const unsigned char* ab[3][2];
#pragma unroll
    for (int dx = 0; dx < 3; ++dx)
#pragma unroll
        for (int ks = 0; ks < 2; ++ks) {
            int xx = px0 + l31 + dx;                 // 0..129
            int q = ks * 2 + hi;
            int slot = (((xx & 1) << 2) | q) ^ ((xx >> 1) & 7);
            ab[dx][ks] = in_sm + (xx >> 1) * 128 + slot * 16;
        }
    // B-frag pointers [n][kstep]: row = n*32 + (lane&31), elem = tap*32 + ks*16 + hi*8
    const unsigned short* bbp[2][2];
#pragma unroll
    for (int n = 0; n < 2; ++n)
#pragma unroll
        for (int ks = 0; ks < 2; ++ks)
            bbp[n][ks] = w_sm + (n * 32 + l31) * WROW + ks * 16 + hi * 8;

    // staging geometry: thread -> (p = gx/2, q = ci oct, rr = row parity)
    const int p_ = tid & 63, q_ = (tid >> 6) & 3, rr_ = tid >> 8;
    const int slotA = (4 | q_) ^ (p_ & 7);                 // xx = 2p+1 (odd)
    const int dstA = p_ * 128 + slotA * 16;
    const int slotB = q_ ^ ((p_ + 1) & 7);                 // xx = 2p+2 (even)
    const int dstB = (p_ + 1) * 128 + slotB * 16;

    for (int cc = 0; cc < 2; ++cc) {
        __syncthreads();
        // ---- stage weights: linear pre-padded copy, 2400 x 16B ----
        const unsigned short* wsrc = wb + cc * (64 * WROW);
        for (int j = tid; j < 2400; j += 512)
            *(uint4*)(w_sm + j * 8) = *(const uint4*)(wsrc + j * 8);
        // ---- stage input: 2 passes x (8 float2 loads -> 8 cvt_pk -> 2 b128 writes) ----
        const float* xq = x + ((size_t)b * 64 + cc * 32 + q_ * 8) * 16384;
#pragma unroll
        for (int pass = 0; pass < 2; ++pass) {
            const int r = pass * 2 + rr_;
            const int gy = y0 + r - 1;
            uint4 A = {0u, 0u, 0u, 0u}, Bv = {0u, 0u, 0u, 0u};
            if ((unsigned)gy < 128u) {               // wave-uniform branch
                const float* src = xq + gy * 128 + 2 * p_;
                float2 f[8];
#pragma unroll
                for (int c = 0; c < 8; ++c) f[c] = *(const float2*)(src + (size_t)c * 16384);
                A.x = pk2bf(f[0].x, f[1].x); A.y = pk2bf(f[2].x, f[3].x);
                A.z = pk2bf(f[4].x, f[5].x); A.w = pk2bf(f[6].x, f[7].x);
                Bv.x = pk2bf(f[0].y, f[1].y); Bv.y = pk2bf(f[2].y, f[3].y);
                Bv.z = pk2bf(f[4].y, f[5].y); Bv.w = pk2bf(f[6].y, f[7].y);
            }
            *(uint4*)(in_sm + r * ROW_BYTES + dstA) = A;
            *(uint4*)(in_sm + r * ROW_BYTES + dstB) = Bv;
        }
        // ---- tail: zero xx=0 (pair0,odd0) and xx=129 (pair64,odd1), all 4 rows ----
        if (tid < 32) {
            int q = tid & 3, r = (tid >> 2) & 3, which = tid >> 4;
            int dst = which == 0 ? (q * 16) : (64 * 128 + (4 | q) * 16);
            *(uint4*)(in_sm + r * ROW_BYTES + dst) = (uint4){0u, 0u, 0u, 0u};
        }
        __syncthreads();

        // ---- compute: 9 taps x 2 k-steps x 2 n-tiles of 32x32x16 ----
#pragma unroll
        for (int t = 0; t < 9; ++t) {
            const int dy = t / 3, dx = t % 3;
            const int aoff = (ro + dy) * ROW_BYTES;
            short8 A0 = *(const short8*)(ab[dx][0] + aoff);
            short8 A1 = *(const short8*)(ab[dx][1] + aoff);
#pragma unroll
            for (int n = 0; n < 2; ++n) {
                short8 B0 = *(const short8*)(bbp[n][0] + t * 32);
                short8 B1 = *(const short8*)(bbp[n][1] + t * 32);
                acc[n] = __builtin_amdgcn_mfma_f32_32x32x16_bf16(A0, B0, acc[n], 0, 0, 0);
                acc[n] = __builtin_amdgcn_mfma_f32_32x32x16_bf16(A1, B1, acc[n], 0, 0, 0);
            }
        }
    }

    // ---- epilogue: bias + leaky relu, bf16 NHWC store ----
    // D: col = n*32 + (lane&31) = co; row = (reg&3) + 8*(reg>>2) + 4*hi = px offset
    float bias[2];
#pragma unroll
    for (int n = 0; n < 2; ++n) bias[n] = cb[n * 32 + l31];
    const size_t hrow = (size_t)(b * 128 + y) * 128;
#pragma unroll
    for (int n = 0; n < 2; ++n)
#pragma unroll
        for (int reg = 0; reg < 16; ++reg) {
            const int px = px0 + (reg & 3) + 8 * (reg >> 2) + 4 * hi;
            float v = acc[n][reg] + bias[n];
            v = v > 0.0f ? v : NEG_SLOPE * v;
            h[(hrow + px) * 64 + n * 32 + l31] = f2bf(v);
        }
}

// ---------------- gather + (pairs x 768)·(768 x 24) GEMM via MFMA ----------------
__global__ __launch_bounds__(256) void gather_gemm(const unsigned short* __restrict__ h,
                                                   const int* __restrict__ pos,
                                                   const unsigned short* __restrict__ pw,
                                                   const float* __restrict__ pred_b,
                                                   float* __restrict__ out) {
    __shared__ unsigned char pw_lds[32 * 1536];   // 32 rows x 768 bf16, swizzled
    const int tid = threadIdx.x;

    for (int i = tid; i < 3072; i += 256) {       // 3072 chunks of 16B
        int row = i / 96, c = i - row * 96;
        int dst = row * 1536 + ((c * 16) ^ ((row & 7) << 4));
        *(uint4*)(pw_lds + dst) = ((const uint4*)pw)[i];
    }
    __syncthreads();

    const int wave = tid >> 6, lane = tid & 63;
    const int pair_base = blockIdx.x * 64 + wave * 16;
    const int prow = lane & 15;
    const int kgrp = lane >> 4;
    const int pair = pair_base + prow;
    const int b = pair & 31;
    const unsigned short* hb = h + (size_t)b * 16384 * 64;

    const int swz0 = (prow & 7) << 4;
    const unsigned char* bro0 = pw_lds + prow * 1536;
    const unsigned char* bro1 = pw_lds + (prow + 16) * 1536;

    f32x4 acc0 = {0.f, 0.f, 0.f, 0.f};
    f32x4 acc1 = {0.f, 0.f, 0.f, 0.f};

#pragma unroll
    for (int l = 0; l < 12; ++l) {
        int2 pq = ((const int2*)pos)[pair * 12 + l];
        int px = pq.x < 0 ? 0 : (pq.x > 127 ? 127 : pq.x);
        int py = pq.y < 0 ? 0 : (pq.y > 127 ? 127 : pq.y);
        const unsigned short* pix = hb + (((size_t)py << 7) + px) * 64;
#pragma unroll
        for (int half = 0; half < 2; ++half) {
            const int c0 = half * 32 + kgrp * 8;
            short8 a = *(const short8*)(pix + c0);
            const int kb = (l * 64 + half * 32 + kgrp * 8) * 2;
            short8 b0 = *(const short8*)(bro0 + (kb ^ swz0));
            short8 b1 = *(const short8*)(bro1 + (kb ^ swz0));
            acc0 = __builtin_amdgcn_mfma_f32_16x16x32_bf16(a, b0, acc0, 0, 0, 0);
            acc1 = __builtin_amdgcn_mfma_f32_16x16x32_bf16(a, b1, acc1, 0, 0, 0);
        }
    }

    const int o0 = lane & 15;
    const float bias0 = pred_b[o0];
    const float bias1 = (o0 + 16 < 24) ? pred_b[o0 + 16] : 0.0f;
#pragma unroll
    for (int r = 0; r < 4; ++r) {
        const int pout = pair_base + (lane >> 4) * 4 + r;
        out[(size_t)pout * 24 + o0] = acc0[r] + bias0;
        if (o0 + 16 < 24)
            out[(size_t)pout * 24 + o0 + 16] = acc1[r] + bias1;
    }
}

extern "C" void kernel_launch(void* const* d_in, const int* in_sizes, int n_in,
                              void* d_out, int out_size, void* d_ws, size_t ws_size,
                              hipStream_t stream) {
    const float* x      = (const float*)d_in[0];
    const int*   pos    = (const int*)d_in[1];
    const float* conv_w = (const float*)d_in[2];
    const float* conv_b = (const float*)d_in[3];
    const float* pred_w = (const float*)d_in[4];
    const float* pred_b = (const float*)d_in[5];
    float* out = (float*)d_out;

    char* ws = (char*)d_ws;
    unsigned short* h   = (unsigned short*)ws;                        // 67,108,864 B
    unsigned short* wb  = (unsigned short*)(ws + 67108864);           // 2*64*300*2 = 76,800 B
    unsigned short* pwb = (unsigned short*)(ws + 67108864 + 76800);   // 49,152 B

    prep_kernel<<<160, 256, 0, stream>>>(conv_w, pred_w, wb, pwb);
    conv_mfma<<<2048, 512, 0, stream>>>(x, wb, conv_b, h);
    gather_gemm<<<500, 256, 0, stream>>>(h, pos, pwb, pred_b, out);
}

// Round 12
// 86.036 us; speedup vs baseline: 2.1022x; 2.1022x over previous
//
#include <hip/hip_runtime.h>
#include <hip/hip_bf16.h>

typedef __attribute__((ext_vector_type(8))) short short8;
typedef __attribute__((ext_vector_type(4))) float f32x4;

#define NEG_SLOPE 0.02f

static __device__ __forceinline__ unsigned short f2bf(float f) {
    unsigned int u = __float_as_uint(f);
    u += 0x7fffu + ((u >> 16) & 1u);
    return (unsigned short)(u >> 16);
}

// pack two f32 -> one dword of 2 bf16 (lo, hi) via v_cvt_pk_bf16_f32
static __device__ __forceinline__ unsigned int pk2bf(float lo, float hi) {
    __hip_bfloat162 t = __float22bfloat162_rn(float2{lo, hi});
    unsigned int u;
    __builtin_memcpy(&u, &t, 4);
    return u;
}

#define WROW 304         // elems per co row: 288 used + 16 pad (152 dw == 24 mod 32, ~floor)
#define ROW_BYTES 8320   // 65 pairs * 128

// ---------------- prep: weight transforms ----------------
// wb padded: [cc][co][WROW] bf16; wb[cc][co][tap*32+ci5] = conv_w[co][cc*32+ci5][tap]
// pwb[o][k] = bf16(pred_w[o][k]) for o<24, 0 pad to 32 rows  (32*768 bf16)
__global__ __launch_bounds__(256) void prep_kernel(const float* __restrict__ conv_w,
                                                   const float* __restrict__ pred_w,
                                                   unsigned short* __restrict__ wb,
                                                   unsigned short* __restrict__ pwb) {
    int i = blockIdx.x * 256 + threadIdx.x;
    if (i < 2 * 64 * WROW) {
        int cc = i / (64 * WROW);
        int rem = i - cc * (64 * WROW);
        int co = rem / WROW, e = rem - co * WROW;
        float v = 0.0f;
        if (e < 288) {
            int tap = e >> 5, ci5 = e & 31;
            v = conv_w[(co * 64 + cc * 32 + ci5) * 9 + tap];
        }
        wb[i] = f2bf(v);
    }
    if (i < 24576) {
        int o = i / 768, k = i - o * 768;
        pwb[i] = f2bf(o < 24 ? pred_w[o * 768 + k] : 0.0f);
    }
}

// ---------------- fused conv 3x3 + bias + leaky relu (NCHW f32 in, NHWC bf16 out) ----------------
// block: 512 thr = 8 waves; 2 output rows x 128 px x 64 co. wave = 32 px x 64 co (2m x 4n,
// 8 independent MFMA chains). LDS: weights [64co][WROW] 38,912 B + input 4 x 8320 B
//   = 72,192 B -> 2 blocks/CU, 4 waves/SIMD.
// Staging: thread = 2 adjacent px x 8 ci -> 8 float2 loads (wave = one contiguous 512 B
// channel-row per instr) -> 8 cvt_pk -> 2 ds_write_b128 (bank-floor). T14: chunk-1 loads
// issued right after chunk-0 LDS writes, latency hidden under chunk-0 compute.
// in_sm slot map (proven): pair stride 128 B, slot = ((xx&1)<<2 | ci_oct) ^ ((xx>>1)&7).
__global__ __launch_bounds__(512, 4) void conv_mfma(const float* __restrict__ x,
                                                    const unsigned short* __restrict__ wb,
                                                    const float* __restrict__ cb,
                                                    unsigned short* __restrict__ h) {
    __shared__ unsigned short w_sm[64 * WROW];       // 38,912 B
    __shared__ unsigned char in_sm[4 * ROW_BYTES];   // 33,280 B

    // XCD-chunked swizzle: each XCD owns 16 contiguous y rows (8 y-pairs) x all b
    const int id = blockIdx.x;                       // 2048 blocks
    const int xcd = id & 7, local = id >> 3;
    const int b = local & 31;
    const int y0 = ((xcd << 3) + (local >> 5)) * 2;

    const int tid = threadIdx.x;
    const int wave = tid >> 6, lane = tid & 63;
    const int lr = lane & 15, kg = lane >> 4;
    const int ro = wave >> 2;                        // output row within block (0/1)
    const int px0 = (wave & 3) * 32;                 // px quarter
    const int y = y0 + ro;

    f32x4 acc[2][4];
#pragma unroll
    for (int m = 0; m < 2; ++m)
#pragma unroll
        for (int n = 0; n < 4; ++n) acc[m][n] = (f32x4){0.f, 0.f, 0.f, 0.f};

    // A-frag base offsets (proven pair/slot swizzle), (ro+dy)*ROW_BYTES added at use
    const unsigned char* ab[2][3];
#pragma unroll
    for (int m = 0; m < 2; ++m)
#pragma unroll
        for (int dx = 0; dx < 3; ++dx) {
            int xx = px0 + m * 16 + lr + dx;         // 0..129
            int pair = xx >> 1, odd = xx & 1;
            int slot = ((odd << 2) | kg) ^ (pair & 7);
            ab[m][dx] = in_sm + pair * 128 + slot * 16;
        }
    const unsigned short* bbp[4];
#pragma unroll
    for (int n = 0; n < 4; ++n) bbp[n] = w_sm + (n * 16 + lr) * WROW + kg * 8;

    // staging geometry: thread = (p_ = pair, q_ = ci oct, rr_ = row parity)
    const int p_ = tid & 63, q_ = (tid >> 6) & 3, rr_ = tid >> 8;
    const int slotA = (4 | q_) ^ (p_ & 7);                 // xx = 2p+1 (odd)
    const int dstA = p_ * 128 + slotA * 16;
    const int slotB = q_ ^ ((p_ + 1) & 7);                 // xx = 2p+2 (even)
    const int dstB = (p_ + 1) * 128 + slotB * 16;

    float2 F[2][8];   // in-flight staging registers (indices static under unroll)

#define LOADX(CCI)                                                                 \
    {                                                                              \
        const float* xq_ = x + ((size_t)b * 64 + (CCI) * 32 + q_ * 8) * 16384;     \
        _Pragma("unroll")                                                          \
        for (int pass = 0; pass < 2; ++pass) {                                     \
            const int r_ = pass * 2 + rr_;                                         \
            const int gy_ = y0 + r_ - 1;                                           \
            if ((unsigned)gy_ < 128u) {                                            \
                const float* s_ = xq_ + gy_ * 128 + 2 * p_;                        \
                _Pragma("unroll")                                                  \
                for (int c = 0; c < 8; ++c)                                        \
                    F[pass][c] = *(const float2*)(s_ + (size_t)c * 16384);         \
            } else {                                                               \
                _Pragma("unroll")                                                  \
                for (int c = 0; c < 8; ++c) F[pass][c] = (float2){0.f, 0.f};       \
            }                                                                      \
        }                                                                          \
    }

#define STOREX()                                                                   \
    {                                                                              \
        _Pragma("unroll")                                                          \
        for (int pass = 0; pass < 2; ++pass) {                                     \
            const int r_ = pass * 2 + rr_;                                         \
            uint4 Av, Bv;                                                          \
            Av.x = pk2bf(F[pass][0].x, F[pass][1].x);                              \
            Av.y = pk2bf(F[pass][2].x, F[pass][3].x);                              \
            Av.z = pk2bf(F[pass][4].x, F[pass][5].x);                              \
            Av.w = pk2bf(F[pass][6].x, F[pass][7].x);                              \
            Bv.x = pk2bf(F[pass][0].y, F[pass][1].y);                              \
            Bv.y = pk2bf(F[pass][2].y, F[pass][3].y);                              \
            Bv.z = pk2bf(F[pass][4].y, F[pass][5].y);                              \
            Bv.w = pk2bf(F[pass][6].y, F[pass][7].y);                              \
            *(uint4*)(in_sm + r_ * ROW_BYTES + dstA) = Av;                         \
            *(uint4*)(in_sm + r_ * ROW_BYTES + dstB) = Bv;                         \
        }                                                                          \
    }

#define STAGEW(CCI)                                                                \
    {                                                                              \
        const unsigned short* wsrc_ = wb + (CCI) * (64 * WROW);                    \
        for (int j = tid; j < 2432; j += 512)                                      \
            *(uint4*)(w_sm + j * 8) = *(const uint4*)(wsrc_ + j * 8);              \
    }

#define TAILZ()                                                                    \
    if (tid < 32) {                                                                \
        int q = tid & 3, r = (tid >> 2) & 3, which = tid >> 4;                     \
        int dst = which == 0 ? (q * 16) : (64 * 128 + (4 | q) * 16);               \
        *(uint4*)(in_sm + r * ROW_BYTES + dst) = (uint4){0u, 0u, 0u, 0u};          \
    }

#define COMPUTE()                                                                  \
    _Pragma("unroll")                                                              \
    for (int t = 0; t < 9; ++t) {                                                  \
        const int dy = t / 3, dx = t % 3;                                          \
        const int aoff = (ro + dy) * ROW_BYTES;                                    \
        short8 A0 = *(const short8*)(ab[0][dx] + aoff);                            \
        short8 A1 = *(const short8*)(ab[1][dx] + aoff);                            \
        _Pragma("unroll")                                                          \
        for (int n = 0; n < 4; ++n) {                                              \
            short8 B = *(const short8*)(bbp[n] + t * 32);                          \
            acc[0][n] = __builtin_amdgcn_mfma_f32_16x16x32_bf16(A0, B, acc[0][n], 0, 0, 0); \
            acc[1][n] = __builtin_amdgcn_mfma_f32_16x16x32_bf16(A1, B, acc[1][n], 0, 0, 0); \
        }                                                                          \
    }

    // ---- chunk 0 ----
    LOADX(0)
    STAGEW(0)
    STOREX()
    TAILZ()
    LOADX(1)            // T14: chunk-1 loads in flight across chunk-0 compute
    __syncthreads();
    COMPUTE()
    // ---- chunk 1 ----
    __syncthreads();
    STAGEW(1)
    STOREX()
    TAILZ()
    __syncthreads();
    COMPUTE()

#undef LOADX
#undef STOREX
#undef STAGEW
#undef TAILZ
#undef COMPUTE

    // ---- epilogue: bias + leaky relu, bf16 NHWC store ----
    float bias[4];
#pragma unroll
    for (int n = 0; n < 4; ++n) bias[n] = cb[n * 16 + lr];
    const size_t hrow = (size_t)(b * 128 + y) * 128;
#pragma unroll
    for (int m = 0; m < 2; ++m)
#pragma unroll
        for (int rr = 0; rr < 4; ++rr) {
            const int p = px0 + m * 16 + kg * 4 + rr;
            unsigned short* hp = h + (hrow + p) * 64 + lr;
#pragma unroll
            for (int n = 0; n < 4; ++n) {
                float v = acc[m][n][rr] + bias[n];
                v = v > 0.0f ? v : NEG_SLOPE * v;
                hp[n * 16] = f2bf(v);
            }
        }
}

// ---------------- gather + (pairs x 768)·(768 x 24) GEMM via MFMA ----------------
__global__ __launch_bounds__(256) void gather_gemm(const unsigned short* __restrict__ h,
                                                   const int* __restrict__ pos,
                                                   const unsigned short* __restrict__ pw,
                                                   const float* __restrict__ pred_b,
                                                   float* __restrict__ out) {
    __shared__ unsigned char pw_lds[32 * 1536];   // 32 rows x 768 bf16, swizzled
    const int tid = threadIdx.x;

    for (int i = tid; i < 3072; i += 256) {       // 3072 chunks of 16B
        int row = i / 96, c = i - row * 96;
        int dst = row * 1536 + ((c * 16) ^ ((row & 7) << 4));
        *(uint4*)(pw_lds + dst) = ((const uint4*)pw)[i];
    }
    __syncthreads();

    const int wave = tid >> 6, lane = tid & 63;
    const int pair_base = blockIdx.x * 64 + wave * 16;
    const int prow = lane & 15;
    const int kgrp = lane >> 4;
    const int pair = pair_base + prow;
    const int b = pair & 31;
    const unsigned short* hb = h + (size_t)b * 16384 * 64;

    const int swz0 = (prow & 7) << 4;
    const unsigned char* bro0 = pw_lds + prow * 1536;
    const unsigned char* bro1 = pw_lds + (prow + 16) * 1536;

    f32x4 acc0 = {0.f, 0.f, 0.f, 0.f};
    f32x4 acc1 = {0.f, 0.f, 0.f, 0.f};

#pragma unroll
    for (int l = 0; l < 12; ++l) {
        int2 pq = ((const int2*)pos)[pair * 12 + l];
        int px = pq.x < 0 ? 0 : (pq.x > 127 ? 127 : pq.x);
        int py = pq.y < 0 ? 0 : (pq.y > 127 ? 127 : pq.y);
        const unsigned short* pix = hb + (((size_t)py << 7) + px) * 64;
#pragma unroll
        for (int half = 0; half < 2; ++half) {
            const int c0 = half * 32 + kgrp * 8;
            short8 a = *(const short8*)(pix + c0);
            const int kb = (l * 64 + half * 32 + kgrp * 8) * 2;
            short8 b0 = *(const short8*)(bro0 + (kb ^ swz0));
            short8 b1 = *(const short8*)(bro1 + (kb ^ swz0));
            acc0 = __builtin_amdgcn_mfma_f32_16x16x32_bf16(a, b0, acc0, 0, 0, 0);
            acc1 = __builtin_amdgcn_mfma_f32_16x16x32_bf16(a, b1, acc1, 0, 0, 0);
        }
    }

    const int o0 = lane & 15;
    const float bias0 = pred_b[o0];
    const float bias1 = (o0 + 16 < 24) ? pred_b[o0 + 16] : 0.0f;
#pragma unroll
    for (int r = 0; r < 4; ++r) {
        const int pout = pair_base + (lane >> 4) * 4 + r;
        out[(size_t)pout * 24 + o0] = acc0[r] + bias0;
        if (o0 + 16 < 24)
            out[(size_t)pout * 24 + o0 + 16] = acc1[r] + bias1;
    }
}

extern "C" void kernel_launch(void* const* d_in, const int* in_sizes, int n_in,
                              void* d_out, int out_size, void* d_ws, size_t ws_size,
                              hipStream_t stream) {
    const float* x      = (const float*)d_in[0];
    const int*   pos    = (const int*)d_in[1];
    const float* conv_w = (const float*)d_in[2];
    const float* conv_b = (const float*)d_in[3];
    const float* pred_w = (const float*)d_in[4];
    const float* pred_b = (const float*)d_in[5];
    float* out = (float*)d_out;

    char* ws = (char*)d_ws;
    unsigned short* h   = (unsigned short*)ws;                        // 67,108,864 B
    unsigned short* wb  = (unsigned short*)(ws + 67108864);           // 2*64*304*2 = 77,824 B
    unsigned short* pwb = (unsigned short*)(ws + 67108864 + 77824);   // 49,152 B

    prep_kernel<<<152, 256, 0, stream>>>(conv_w, pred_w, wb, pwb);
    conv_mfma<<<2048, 512, 0, stream>>>(x, wb, conv_b, h);
    gather_gemm<<<500, 256, 0, stream>>>(h, pos, pwb, pred_b, out);
}